// Round 1
// baseline (167.184 us; speedup 1.0000x reference)
//
#include <hip/hip_runtime.h>
#include <hip/hip_fp16.h>

#define T_TOK 200
#define EMB   128

typedef _Float16 f16x8 __attribute__((ext_vector_type(8)));
typedef float    f32x4 __attribute__((ext_vector_type(4)));

// pack 8 consecutive fp32 -> f16x8 in the same element order the R12
// prep pack produced (so all MFMA frag layouts stay identical)
__device__ __forceinline__ f16x8 cvt8(float4 a, float4 b)
{
    __half2 hh[4];
    hh[0] = __floats2half2_rn(a.x, a.y);
    hh[1] = __floats2half2_rn(a.z, a.w);
    hh[2] = __floats2half2_rn(b.x, b.y);
    hh[3] = __floats2half2_rn(b.z, b.w);
    return *(f16x8*)hh;
}

// ---- single fused kernel: pool (fp32 gather) + MFMA MLP ----
// 1024 thr = 16 waves, 16 samples/block, grid N/16.
// No workspace, no prep pass: emb gathered fp32 (L3-resident either way),
// W-frags loaded fp32 + converted in-register with the inverse pack map:
//   o = ot*16 + (lane&15), k0 = kc*32 + (lane>>4)*8, elems W[o][k0..k0+8)
__global__ __launch_bounds__(1024) void fused_kernel(
    const int* __restrict__ x, const int* __restrict__ lengths,
    const float* __restrict__ emb,
    const float* __restrict__ W1, const float* __restrict__ b1,
    const float* __restrict__ W2, const float* __restrict__ b2,
    const float* __restrict__ W3, const float* __restrict__ b3,
    const float* __restrict__ W4, const float* __restrict__ b4,
    float* __restrict__ out)
{
    __shared__ __align__(16) _Float16 A0[16 * 136];
    __shared__ __align__(16) _Float16 H1[16 * 520];
    __shared__ __align__(16) _Float16 H2[16 * 264];
    __shared__ __align__(16) _Float16 H3[16 * 136];

    const int tid  = threadIdx.x;
    const int wid  = tid >> 6;            // 0..15
    const int lane = tid & 63;
    const int base = blockIdx.x * 16;
    const int n15  = lane & 15;
    const int quad = lane >> 4;

    // ---- L1 W-frags: direct fp32 load + cvt, prefetched before pool so
    //      the load latency hides behind the gather phase ----
    f16x8 w1f[2][4];
#pragma unroll
    for (int ot = 0; ot < 2; ++ot)
#pragma unroll
        for (int kc = 0; kc < 4; ++kc) {
            const float* s = W1 + (size_t)((wid * 2 + ot) * 16 + n15) * 128
                                + kc * 32 + quad * 8;
            float4 f0 = *(const float4*)s;
            float4 f1 = *(const float4*)(s + 4);
            w1f[ot][kc] = cvt8(f0, f1);
        }

    // ---- pool phase: wave wid pools sample base+wid, fp32 gather.
    //      32 lanes per 512B row, 32 tokens in flight (16 float4/lane) ----
    {
        const int n   = base + wid;
        const int len = lengths[n];
        const int* xr = x + (size_t)n * T_TOK;

        int r0 = xr[lane];
        int r1 = xr[64 + lane];
        int r2 = xr[128 + lane];
        int r3 = xr[(192 + lane < T_TOK) ? (192 + lane) : (T_TOK - 1)];

        const int part = lane >> 5;       // 0..1: token slot parity
        const int sub  = lane & 31;       // 0..31: float4 index in row
        float acc[4];
#pragma unroll
        for (int j = 0; j < 4; ++j) acc[j] = 0.f;

        for (int c = 0; c < 4; ++c) {
            const int coff = c * 64;
            if (coff >= len) break;
            int m = len - coff;
            if (m > 64) m = 64;
            int r = r0;
            if (c == 1) r = r1;
            if (c == 2) r = r2;
            if (c == 3) r = r3;

            for (int k = 0; k < m; k += 32) {   // 16 quad-loads in flight
                float4 v[16];
#pragma unroll
                for (int i = 0; i < 16; ++i) {
                    int t  = k + 2 * i + part;
                    int tc = (t < m) ? t : (m - 1);   // clamp: dup row, ~free
                    int idx = __shfl(r, tc);
                    v[i] = *(const float4*)(emb + (size_t)idx * EMB + sub * 4);
                }
#pragma unroll
                for (int i = 0; i < 16; ++i) {
                    int t = k + 2 * i + part;
                    if (t < m) {
                        acc[0] += v[i].x; acc[1] += v[i].y;
                        acc[2] += v[i].z; acc[3] += v[i].w;
                    }
                }
            }
        }
#pragma unroll
        for (int j = 0; j < 4; ++j)
            acc[j] += __shfl(acc[j], lane ^ 32);

        if (part == 0) {
            const float inv = 1.0f / (float)len;
            __half2 p[2];
            p[0] = __floats2half2_rn(acc[0] * inv, acc[1] * inv);
            p[1] = __floats2half2_rn(acc[2] * inv, acc[3] * inv);
            *(float2*)&A0[wid * 136 + sub * 4] = *(float2*)p;
        }
    }
    __syncthreads();

    // ---- L1: 128 -> 512, W already in registers ----
    {
        f16x8 a[4];
#pragma unroll
        for (int kc = 0; kc < 4; ++kc)
            a[kc] = *(const f16x8*)&A0[n15 * 136 + kc * 32 + quad * 8];

        f32x4 acc[2];
        acc[0] = (f32x4){0.f, 0.f, 0.f, 0.f};
        acc[1] = (f32x4){0.f, 0.f, 0.f, 0.f};

#pragma unroll
        for (int kc = 0; kc < 4; ++kc)
#pragma unroll
            for (int ot = 0; ot < 2; ++ot)
                acc[ot] = __builtin_amdgcn_mfma_f32_16x16x32_f16(a[kc], w1f[ot][kc], acc[ot], 0, 0, 0);

#pragma unroll
        for (int ot = 0; ot < 2; ++ot) {
            int o = (wid * 2 + ot) * 16 + n15;
            float bias = b1[o];
#pragma unroll
            for (int r = 0; r < 4; ++r) {
                float v = acc[ot][r] + bias;
                H1[(quad * 4 + r) * 520 + o] = (_Float16)fmaxf(v, 0.f);
            }
        }
    }
    __syncthreads();

    // ---- L2: 512 -> 256, kc batched x4 (8 global loads in flight) ----
    {
        f32x4 acc = (f32x4){0.f, 0.f, 0.f, 0.f};
#pragma unroll
        for (int kb = 0; kb < 4; ++kb) {
            f16x8 bfr[4], afr[4];
#pragma unroll
            for (int i = 0; i < 4; ++i) {
                int kc = kb * 4 + i;
                const float* s = W2 + (size_t)(wid * 16 + n15) * 512
                                    + kc * 32 + quad * 8;
                float4 f0 = *(const float4*)s;
                float4 f1 = *(const float4*)(s + 4);
                bfr[i] = cvt8(f0, f1);
                afr[i] = *(const f16x8*)&H1[n15 * 520 + kc * 32 + quad * 8];
            }
#pragma unroll
            for (int i = 0; i < 4; ++i)
                acc = __builtin_amdgcn_mfma_f32_16x16x32_f16(afr[i], bfr[i], acc, 0, 0, 0);
        }
        int o = wid * 16 + n15;
        float bias = b2[o];
#pragma unroll
        for (int r = 0; r < 4; ++r) {
            float v = acc[r] + bias;
            H2[(quad * 4 + r) * 264 + o] = (_Float16)fmaxf(v, 0.f);
        }
    }
    __syncthreads();

    // ---- L3: 256 -> 128, waves 0..7, all 8 frags batched ----
    if (wid < 8) {
        f16x8 bfr[8], afr[8];
#pragma unroll
        for (int kc = 0; kc < 8; ++kc) {
            const float* s = W3 + (size_t)(wid * 16 + n15) * 256
                                + kc * 32 + quad * 8;
            float4 f0 = *(const float4*)s;
            float4 f1 = *(const float4*)(s + 4);
            bfr[kc] = cvt8(f0, f1);
            afr[kc] = *(const f16x8*)&H2[n15 * 264 + kc * 32 + quad * 8];
        }
        f32x4 acc = (f32x4){0.f, 0.f, 0.f, 0.f};
#pragma unroll
        for (int kc = 0; kc < 8; ++kc)
            acc = __builtin_amdgcn_mfma_f32_16x16x32_f16(afr[kc], bfr[kc], acc, 0, 0, 0);

        int o = wid * 16 + n15;
        float bias = b3[o];
#pragma unroll
        for (int r = 0; r < 4; ++r) {
            float v = acc[r] + bias;
            H3[(quad * 4 + r) * 136 + o] = (_Float16)fmaxf(v, 0.f);
        }
    }
    __syncthreads();

    // ---- L4: 128 -> 2 ----
    if (tid < 32) {
        int s = tid >> 1;
        int o = tid & 1;
        float accv = b4[o];
        const _Float16* xr = &H3[s * 136];
        const float* wr = &W4[(size_t)o * EMB];
#pragma unroll 8
        for (int f = 0; f < EMB; ++f) accv = fmaf((float)xr[f], wr[f], accv);
        out[(size_t)(base + s) * 2 + o] = accv;
    }
}

extern "C" void kernel_launch(void* const* d_in, const int* in_sizes, int n_in,
                              void* d_out, int out_size, void* d_ws, size_t ws_size,
                              hipStream_t stream)
{
    const int*   x       = (const int*)d_in[0];
    const int*   lengths = (const int*)d_in[1];
    const float* emb     = (const float*)d_in[2];
    const float* W1      = (const float*)d_in[3];
    const float* b1      = (const float*)d_in[4];
    const float* W2      = (const float*)d_in[5];
    const float* b2      = (const float*)d_in[6];
    const float* W3      = (const float*)d_in[7];
    const float* b3      = (const float*)d_in[8];
    const float* W4      = (const float*)d_in[9];
    const float* b4      = (const float*)d_in[10];
    float*       out     = (float*)d_out;

    const int N = in_sizes[1];   // 4096

    (void)d_ws; (void)ws_size;   // workspace intentionally unused:
                                 // avoids the per-iteration prep re-run
                                 // forced by ws re-poison semantics

    fused_kernel<<<N / 16, 1024, 0, stream>>>(x, lengths, emb,
        W1, b1, W2, b2, W3, b3, W4, b4, out);
}